// Round 1
// 186.265 us; speedup vs baseline: 1.0190x; 1.0190x over previous
//
#include <hip/hip_runtime.h>
#include <stdint.h>

#define DI __device__ __forceinline__

typedef unsigned short u16;
typedef __bf16 bf16x8 __attribute__((ext_vector_type(8)));
typedef unsigned short u16x8 __attribute__((ext_vector_type(8)));
typedef unsigned short u16x4 __attribute__((ext_vector_type(4)));
typedef float f32x4 __attribute__((ext_vector_type(4)));
typedef float f32x16 __attribute__((ext_vector_type(16)));
typedef unsigned int u32x2 __attribute__((ext_vector_type(2)));
typedef unsigned int u32x4 __attribute__((ext_vector_type(4)));

DI u16 f2bf(float f) { __bf16 h = (__bf16)f; return __builtin_bit_cast(u16, h); }
DI float bf2f(u16 u) { return (float)__builtin_bit_cast(__bf16, u); }

DI bf16x8 ld8(const u16* p) { return __builtin_bit_cast(bf16x8, *(const u16x8*)p); }

DI f32x4 mfma16(bf16x8 a, bf16x8 b, f32x4 c) {
  return __builtin_amdgcn_mfma_f32_16x16x32_bf16(a, b, c, 0, 0, 0);
}
DI f32x16 mfma32(bf16x8 a, bf16x8 b, f32x16 c) {
  return __builtin_amdgcn_mfma_f32_32x32x16_bf16(a, b, c, 0, 0, 0);
}

// v_cvt_pk_bf16_f32: no builtin on gfx950 (T12 recipe) — dst.lo=bf16(a), dst.hi=bf16(b)
DI unsigned pkbf(float a, float b) {
  unsigned r;
  asm("v_cvt_pk_bf16_f32 %0, %1, %2" : "=v"(r) : "v"(a), "v"(b));
  return r;
}

DI void async16(const u16* g, u16* l) {
  __builtin_amdgcn_global_load_lds((const __attribute__((address_space(1))) void*)g,
                                   (__attribute__((address_space(3))) void*)l, 16, 0, 0);
}

// ---------------- fused cast fp32 -> bf16 for x / qkv_w / proj_w ----------------
__global__ __launch_bounds__(256) void cast_all(const float* __restrict__ x,
                                                const float* __restrict__ qw,
                                                const float* __restrict__ pw,
                                                u16* __restrict__ xb, u16* __restrict__ qwb,
                                                u16* __restrict__ pwb) {
  const int bi = blockIdx.x;
  const float* src;
  u16* dst;
  int off;
  if (bi < 4096) {
    src = x; dst = xb; off = bi;
  } else if (bi < 7168) {
    src = qw; dst = qwb; off = bi - 4096;
  } else {
    src = pw; dst = pwb; off = bi - 7168;
  }
  const int i = off * 256 + threadIdx.x;
  const float4 v = ((const float4*)src)[i];
  u16x4 o = {f2bf(v.x), f2bf(v.y), f2bf(v.z), f2bf(v.w)};
  ((u16x4*)dst)[i] = o;
}

// ---------------- GEMM: out[M,N] = A[M,K] @ W[N,K]^T (bf16 in, fp32 acc) ----------------
// 128x128 tile, BK=32, 256 threads = 4 waves (2x2), double-buffered LDS staging.
template <int OUT_BF16>
__global__ __launch_bounds__(256) void gemm_bt(const u16* __restrict__ A,
                                               const u16* __restrict__ W,
                                               void* __restrict__ outp,
                                               int M, int N, int K) {
  __shared__ u16 sA[2 * 4096];
  __shared__ u16 sB[2 * 4096];
  const int tid = threadIdx.x;
  const int w = tid >> 6, L = tid & 63;
  const int lo = L & 15, quad = L >> 4;
  const int nb = N >> 7;
  const int bm = blockIdx.x / nb, bn = blockIdx.x - bm * nb;
  const int m0 = bm << 7, n0 = bn << 7;
  const int wm = (w >> 1) << 6, wn = (w & 1) << 6;

  f32x4 acc[4][4];
#pragma unroll
  for (int i = 0; i < 4; ++i)
#pragma unroll
    for (int j = 0; j < 4; ++j) acc[i][j] = 0.f;

  const int r0 = tid >> 2, s0 = tid & 3;
  const int c0 = s0 ^ ((r0 >> 1) & 3);
  const int r1 = r0 + 64;
  const int c1 = s0 ^ ((r1 >> 1) & 3);
  const u16* aP0 = A + (size_t)(m0 + r0) * K + c0 * 8;
  const u16* aP1 = A + (size_t)(m0 + r1) * K + c1 * 8;
  const u16* bP0 = W + (size_t)(n0 + r0) * K + c0 * 8;
  const u16* bP1 = W + (size_t)(n0 + r1) * K + c1 * 8;
  u16* ldA0 = &sA[tid * 8];
  u16* ldA1 = &sA[(tid + 256) * 8];
  u16* ldB0 = &sB[tid * 8];
  u16* ldB1 = &sB[(tid + 256) * 8];

  int raf[4], rbf[4];
#pragma unroll
  for (int mt = 0; mt < 4; ++mt) {
    int r = wm + mt * 16 + lo;
    raf[mt] = r * 32 + ((quad ^ ((r >> 1) & 3)) << 3);
    r = wn + mt * 16 + lo;
    rbf[mt] = r * 32 + ((quad ^ ((r >> 1) & 3)) << 3);
  }

  auto stage = [&](int buf) {
    const int bo = buf << 12;
    async16(aP0, ldA0 + bo);
    async16(aP1, ldA1 + bo);
    async16(bP0, ldB0 + bo);
    async16(bP1, ldB1 + bo);
    aP0 += 32; aP1 += 32; bP0 += 32; bP1 += 32;
  };

  const int kIters = K >> 5;
  stage(0);
  for (int kt = 0; kt < kIters; ++kt) {
    __syncthreads();
    if (kt + 1 < kIters) stage((kt + 1) & 1);
    const int bo = (kt & 1) << 12;
    bf16x8 af[4], bfr[4];
#pragma unroll
    for (int mt = 0; mt < 4; ++mt) af[mt] = ld8(&sA[bo + raf[mt]]);
#pragma unroll
    for (int nt = 0; nt < 4; ++nt) bfr[nt] = ld8(&sB[bo + rbf[nt]]);
#pragma unroll
    for (int mt = 0; mt < 4; ++mt)
#pragma unroll
      for (int nt = 0; nt < 4; ++nt)
        acc[mt][nt] = mfma16(af[mt], bfr[nt], acc[mt][nt]);
  }

#pragma unroll
  for (int mt = 0; mt < 4; ++mt) {
    const int m = m0 + wm + mt * 16 + quad * 4;
#pragma unroll
    for (int nt = 0; nt < 4; ++nt) {
      const int n = n0 + wn + nt * 16 + lo;
#pragma unroll
      for (int r = 0; r < 4; ++r) {
        const size_t off = (size_t)(m + r) * N + n;
        if (OUT_BF16)
          ((u16*)outp)[off] = f2bf(acc[mt][nt][r]);
        else
          ((float*)outp)[off] = acc[mt][nt][r];
      }
    }
  }
}

// ---------------- fused RoPE(Q,K) + V transpose ----------------
// blocks [0,8192): rope elementwise; blocks [8192,9216): vt LDS transpose.
#define QSCALE 0.18033688011112f  // 0.125 * log2(e)
__global__ __launch_bounds__(256) void ropevt_k(const u16* __restrict__ qkv,
                                                const float* __restrict__ cosb,
                                                const float* __restrict__ sinb,
                                                u16* __restrict__ qo, u16* __restrict__ ko,
                                                u16* __restrict__ vto) {
  __shared__ u16 sT[64 * 64];
  const int tid = threadIdx.x;
  if (blockIdx.x < 8192) {
    const int idx = blockIdx.x * 256 + tid;  // ((b*16+h)*2048+t)*32 + i
    const int i = idx & 31;
    const int t = (idx >> 5) & 2047;
    const int h = (idx >> 16) & 15;
    const int b = idx >> 20;
    const size_t src = ((size_t)(b * 2048 + t)) * 3072 + h * 64 + 2 * i;
    const float q0v = bf2f(qkv[src]), q1v = bf2f(qkv[src + 1]);
    const float k0v = bf2f(qkv[src + 1024]), k1v = bf2f(qkv[src + 1025]);
    const float c = cosb[t * 32 + i], s = sinb[t * 32 + i];
    const size_t dst = ((size_t)((b * 16 + h) * 2048 + t)) * 64 + 2 * i;
    qo[dst] = f2bf((q0v * c - q1v * s) * QSCALE);
    qo[dst + 1] = f2bf((q0v * s + q1v * c) * QSCALE);
    ko[dst] = f2bf(k0v * c - k1v * s);
    ko[dst + 1] = f2bf(k0v * s + k1v * c);
  } else {
    const int bi = blockIdx.x - 8192;
    const int bh = bi & 31;
    const int t0 = (bi >> 5) << 6;
    const int b = bh >> 4, h = bh & 15;
#pragma unroll
    for (int it = 0; it < 2; ++it) {
      const int id = tid + it * 256;
      const int tr = id >> 3, s = id & 7, c = s ^ (tr & 7);
      async16(qkv + (size_t)(b * 2048 + t0 + tr) * 3072 + 2048 + h * 64 + c * 8, &sT[id * 8]);
    }
    __syncthreads();
#pragma unroll
    for (int it = 0; it < 2; ++it) {
      const int id = tid + it * 256;
      const int d = id >> 3, ct = id & 7;
      u16x8 o;
#pragma unroll
      for (int j = 0; j < 8; ++j) {
        const int t = ct * 8 + j;
        o[j] = sT[t * 64 + (((d >> 3) ^ (t & 7)) << 3) + (d & 7)];
      }
      *(u16x8*)(vto + ((size_t)bh * 64 + d) * 2048 + t0 + ct * 8) = o;
    }
  }
}

// ---------------- causal flash attention, split-KV partials, MAX-FREE softmax ----------------
// 32x32x16 MFMA restructure: 4 waves x 32 q-rows = 128-q blocks, 64-kv tiles.
// Swapped QK^T (A=K rows, B=Q cols) puts a full 32-kv P slice in-lane for one q col;
// softmax is elementwise exp2 (max-free, Q pre-scaled by 0.125*log2e), and P reshapes
// into PV B-fragments IN REGISTER via v_cvt_pk_bf16_f32 + permlane32_swap (T12) —
// no LDS P round-trip, no per-tile lgkmcnt(0) bubble. Row-sum l stays on the MFMA
// pipe (ones-A x P-frags). Emits UNNORMALIZED O (bf16) + l per q row.
__global__ __launch_bounds__(256, 2) void fattn_part(const u16* __restrict__ qs,
                                                     const u16* __restrict__ ks,
                                                     const u16* __restrict__ vtb,
                                                     u16* __restrict__ opart,
                                                     float* __restrict__ lbuf) {
  __shared__ u16 sK[2 * 4096];   // kv-major rows of 128B, chunk slot = c ^ (kv&7)
  __shared__ u16 sVt[2 * 4096];  // d-major rows of 128B, chunk slot = c ^ (d&7)
  const int tid = threadIdx.x;
  const int w = tid >> 6, L = tid & 63;
  const int col = L & 31, hi = L >> 5;
  const int raw = blockIdx.x;
  const int part = raw & 1;
  const int bh = (raw >> 1) & 31;
  const int qb = 15 - (raw >> 6);  // long blocks launch first
  const int n = 2 * qb + 2;        // kv tiles this block needs (causal)
  const int h0 = qb + 1;
  const int tk0 = part ? h0 : 0;
  const int tk1 = part ? n : h0;
  const size_t hoff = (size_t)bh * (2048 * 64);
  const int q0 = qb << 7;
  const int wq = q0 + w * 32;  // this wave's first q row

  // staging pointers (advance per tile); same 64x64 chunk-swizzled layout for K and Vt
  const int kvA = tid >> 3, cA = (tid & 7) ^ (kvA & 7);
  const int idB = tid + 256;
  const int kvB = idB >> 3, cB = (idB & 7) ^ (kvB & 7);
  const u16* kP0 = ks + hoff + (size_t)(tk0 * 64 + kvA) * 64 + cA * 8;
  const u16* kP1 = ks + hoff + (size_t)(tk0 * 64 + kvB) * 64 + cB * 8;
  const u16* vP0 = vtb + hoff + (size_t)kvA * 2048 + tk0 * 64 + cA * 8;
  const u16* vP1 = vtb + hoff + (size_t)kvB * 2048 + tk0 * 64 + cB * 8;
  u16* ldK0 = &sK[tid * 8];
  u16* ldK1 = &sK[idB * 8];
  u16* ldV0 = &sVt[tid * 8];
  u16* ldV1 = &sVt[idB * 8];

  auto stage = [&](int buf) {
    const int bo = buf << 12;
    async16(kP0, ldK0 + bo);
    async16(kP1, ldK1 + bo);
    async16(vP0, ldV0 + bo);
    async16(vP1, ldV1 + bo);
    kP0 += 4096; kP1 += 4096; vP0 += 64; vP1 += 64;
  };

  // A-fragment LDS offsets: row = mt*32 + col, chunk = ks*2 + hi, slot = chunk^(row&7).
  // Identical for sK (row=kv) and sVt (row=d).
  int kaOff[2][4];
#pragma unroll
  for (int mt = 0; mt < 2; ++mt) {
    const int row = mt * 32 + col;
#pragma unroll
    for (int ksI = 0; ksI < 4; ++ksI)
      kaOff[mt][ksI] = row * 64 + (((ksI * 2 + hi) ^ (row & 7)) << 3);
  }

  // Q as B-operand frags (held whole loop): B[k=d][n=q], k = ks*16 + hi*8 + j
  bf16x8 qf[4];
#pragma unroll
  for (int ksI = 0; ksI < 4; ++ksI)
    qf[ksI] = ld8(qs + hoff + (size_t)(wq + col) * 64 + ksI * 16 + hi * 8);

  // ones A-operand for the l row-sum MFMA
  bf16x8 ones;
#pragma unroll
  for (int j = 0; j < 8; ++j) ones[j] = (__bf16)1.0f;

  f32x16 lacc = 0.f;
  f32x16 ot0 = 0.f, ot1 = 0.f;

  const int ntk = tk1 - tk0;
  stage(0);
  for (int it2 = 0; it2 < ntk; ++it2) {
    __syncthreads();
    if (it2 + 1 < ntk) stage((it2 + 1) & 1);
    const int bo = (it2 & 1) << 12;
    const int kt = tk0 + it2;

    // fully-masked wave-tile (kv_min > q_max): skip compute, keep barriers
    if (64 * kt <= wq + 31) {
      // QK^T: S[kv][q], kv in two 32-row m-tiles
      f32x16 st0 = 0.f, st1 = 0.f;
#pragma unroll
      for (int ksI = 0; ksI < 4; ++ksI) {
        st0 = mfma32(ld8(&sK[bo + kaOff[0][ksI]]), qf[ksI], st0);
        st1 = mfma32(ld8(&sK[bo + kaOff[1][ksI]]), qf[ksI], st1);
      }
      if (64 * kt + 63 > wq) {  // diagonal tile: causal mask
        const int qg = wq + col;
        const int kvb = 64 * kt + 4 * hi;
#pragma unroll
        for (int r = 0; r < 16; ++r) {
          const int kvr = kvb + (r & 3) + 8 * (r >> 2);
          if (kvr > qg) st0[r] = -3.0e38f;
          if (kvr + 32 > qg) st1[r] = -3.0e38f;
        }
      }
      // max-free softmax + in-register reshape to PV B-frags.
      // C-layout: lane holds q=col, kv = (r&3)+8*(r>>2)+4*hi (+32 for st1).
      // B-frag for PV k-step ks needs kv = ks*16 + hi*8 + j at the SAME q col:
      // cvt_pk pairs + permlane32_swap (lane <-> lane+32) fills two words per swap.
      bf16x8 pf[4];
#pragma unroll
      for (int mt = 0; mt < 2; ++mt) {
        const f32x16 sv = mt ? st1 : st0;
        f32x16 p;
#pragma unroll
        for (int r = 0; r < 16; ++r) p[r] = __builtin_amdgcn_exp2f(sv[r]);
        {
          unsigned x0 = pkbf(p[0], p[1]), x1 = pkbf(p[2], p[3]);
          unsigned y0 = pkbf(p[4], p[5]), y1 = pkbf(p[6], p[7]);
          u32x2 r02 = __builtin_amdgcn_permlane32_swap(x0, y0, false, false);
          u32x2 r13 = __builtin_amdgcn_permlane32_swap(x1, y1, false, false);
          u32x4 wv = {r02[0], r13[0], r02[1], r13[1]};
          pf[2 * mt] = __builtin_bit_cast(bf16x8, wv);
        }
        {
          unsigned x0 = pkbf(p[8], p[9]), x1 = pkbf(p[10], p[11]);
          unsigned y0 = pkbf(p[12], p[13]), y1 = pkbf(p[14], p[15]);
          u32x2 r02 = __builtin_amdgcn_permlane32_swap(x0, y0, false, false);
          u32x2 r13 = __builtin_amdgcn_permlane32_swap(x1, y1, false, false);
          u32x4 wv = {r02[0], r13[0], r02[1], r13[1]};
          pf[2 * mt + 1] = __builtin_bit_cast(bf16x8, wv);
        }
      }
      // l row-sum on the MFMA pipe (all C rows identical = sum over kv)
#pragma unroll
      for (int ksI = 0; ksI < 4; ++ksI) lacc = mfma32(ones, pf[ksI], lacc);
      // PV: O[d][q] += Vt[d][kv] * P[kv][q]
#pragma unroll
      for (int ksI = 0; ksI < 4; ++ksI) {
        ot0 = mfma32(ld8(&sVt[bo + kaOff[0][ksI]]), pf[ksI], ot0);
        ot1 = mfma32(ld8(&sVt[bo + kaOff[1][ksI]]), pf[ksI], ot1);
      }
    }
  }

  // epilogue: store unnormalized O (bf16) + l; merge kernel normalizes.
  // C-layout: lane holds q=col; d = mtd*32 + (r&3) + 8*(r>>2) + 4*hi.
  const int q = wq + col;
  const int pq = bh * 32 + (q >> 6);
  u16* ob = opart + (size_t)(part * 1024 + pq) * 4096 + (size_t)(q & 63) * 64;
#pragma unroll
  for (int mtd = 0; mtd < 2; ++mtd) {
    const f32x16 o = mtd ? ot1 : ot0;
#pragma unroll
    for (int rg = 0; rg < 4; ++rg) {
      const int d0 = mtd * 32 + rg * 8 + hi * 4;
      u16x4 ok = {f2bf(o[rg * 4 + 0]), f2bf(o[rg * 4 + 1]),
                  f2bf(o[rg * 4 + 2]), f2bf(o[rg * 4 + 3])};
      *(u16x4*)&ob[d0] = ok;
    }
  }
  if (hi == 0) lbuf[(size_t)(part * 1024 + pq) * 64 + (q & 63)] = lacc[0];
}

// ---------------- merge the two kv-half partials -> attn (B,T,C) bf16 ----------------
__global__ __launch_bounds__(256) void fattn_merge(const u16* __restrict__ opart,
                                                   const float* __restrict__ lbuf,
                                                   u16* __restrict__ aout) {
  const int pq = blockIdx.x;
  const int bh = pq >> 5, qi = pq & 31;
  const int b = bh >> 4, h = bh & 15;
  const int tid = threadIdx.x;
#pragma unroll
  for (int it = 0; it < 2; ++it) {
    const int idx = tid + it * 256;
    const int q = idx >> 3, d0 = (idx & 7) * 8;
    const float l0 = lbuf[(size_t)pq * 64 + q];
    const float l1 = lbuf[(size_t)(1024 + pq) * 64 + q];
    const float inv = 1.f / (l0 + l1);
    const u16x8 o0 = *(const u16x8*)&opart[(size_t)pq * 4096 + q * 64 + d0];
    const u16x8 o1 = *(const u16x8*)&opart[(size_t)(1024 + pq) * 4096 + q * 64 + d0];
    u16x8 o;
#pragma unroll
    for (int j = 0; j < 8; ++j) o[j] = f2bf((bf2f(o0[j]) + bf2f(o1[j])) * inv);
    *(u16x8*)&aout[((size_t)(b * 2048 + qi * 64 + q)) * 1024 + h * 64 + d0] = o;
  }
}

extern "C" void kernel_launch(void* const* d_in, const int* in_sizes, int n_in,
                              void* d_out, int out_size, void* d_ws, size_t ws_size,
                              hipStream_t stream) {
  const float* x = (const float*)d_in[0];
  const float* fcos = (const float*)d_in[1];
  const float* fsin = (const float*)d_in[2];
  const float* qkvw = (const float*)d_in[3];
  const float* projw = (const float*)d_in[4];
  float* out = (float*)d_out;

  char* ws = (char*)d_ws;
  u16* x_bf = (u16*)(ws);                    // 8 MB  (4096x1024)
  u16* qkvw_bf = (u16*)(ws + (8u << 20));    // 6 MB  (3072x1024)
  u16* projw_bf = (u16*)(ws + (14u << 20));  // 2 MB  (1024x1024)
  u16* qkv_bf = (u16*)(ws + (16u << 20));    // 24 MB (4096x3072), dead after ropevt
  u16* q_bf = (u16*)(ws + (40u << 20));      // 8 MB  (B,H,T,D)
  u16* k_bf = (u16*)(ws + (48u << 20));      // 8 MB  (B,H,T,D)
  u16* vt = (u16*)(ws + (56u << 20));        // 8 MB  (B,H,D,T)
  u16* attn_bf = (u16*)(ws + (64u << 20));   // 8 MB  (B,T,C)
  // overlays on the dead qkv_bf region:
  u16* opart = (u16*)(ws + (16u << 20));     // 16 MB [2][1024][64q][64d] bf16
  float* lbuf = (float*)(ws + (32u << 20));  // 0.5 MB [2][1024][64q]

  cast_all<<<8192, 256, 0, stream>>>(x, qkvw, projw, x_bf, qkvw_bf, projw_bf);
  gemm_bt<1><<<768, 256, 0, stream>>>(x_bf, qkvw_bf, (void*)qkv_bf, 4096, 3072, 1024);
  ropevt_k<<<9216, 256, 0, stream>>>(qkv_bf, fcos, fsin, q_bf, k_bf, vt);
  fattn_part<<<1024, 256, 0, stream>>>(q_bf, k_bf, vt, opart, lbuf);
  fattn_merge<<<1024, 256, 0, stream>>>(opart, lbuf, attn_bf);
  gemm_bt<0><<<256, 256, 0, stream>>>(attn_bf, projw_bf, (void*)out, 4096, 1024, 1024);
}

// Round 3
// 181.828 us; speedup vs baseline: 1.0439x; 1.0244x over previous
//
#include <hip/hip_runtime.h>
#include <stdint.h>

#define DI __device__ __forceinline__

typedef unsigned short u16;
typedef __bf16 bf16x8 __attribute__((ext_vector_type(8)));
typedef unsigned short u16x8 __attribute__((ext_vector_type(8)));
typedef unsigned short u16x4 __attribute__((ext_vector_type(4)));
typedef float f32x4 __attribute__((ext_vector_type(4)));
typedef float f32x16 __attribute__((ext_vector_type(16)));
typedef unsigned int u32x2 __attribute__((ext_vector_type(2)));
typedef unsigned int u32x4 __attribute__((ext_vector_type(4)));

DI u16 f2bf(float f) { __bf16 h = (__bf16)f; return __builtin_bit_cast(u16, h); }
DI float bf2f(u16 u) { return (float)__builtin_bit_cast(__bf16, u); }

DI bf16x8 ld8(const u16* p) { return __builtin_bit_cast(bf16x8, *(const u16x8*)p); }

DI f32x4 mfma16(bf16x8 a, bf16x8 b, f32x4 c) {
  return __builtin_amdgcn_mfma_f32_16x16x32_bf16(a, b, c, 0, 0, 0);
}
DI f32x16 mfma32(bf16x8 a, bf16x8 b, f32x16 c) {
  return __builtin_amdgcn_mfma_f32_32x32x16_bf16(a, b, c, 0, 0, 0);
}

// v_cvt_pk_bf16_f32: no builtin on gfx950 (T12 recipe) — dst.lo=bf16(a), dst.hi=bf16(b)
DI unsigned pkbf(float a, float b) {
  unsigned r;
  asm("v_cvt_pk_bf16_f32 %0, %1, %2" : "=v"(r) : "v"(a), "v"(b));
  return r;
}

DI void async16(const u16* g, u16* l) {
  __builtin_amdgcn_global_load_lds((const __attribute__((address_space(1))) void*)g,
                                   (__attribute__((address_space(3))) void*)l, 16, 0, 0);
}

// raw workgroup barrier with COMPILER memory fences (no hw waitcnt): guarantees the
// emitted instruction order matches the source-level phase ledger.
DI void barC() {
  asm volatile("" ::: "memory");
  __builtin_amdgcn_s_barrier();
  asm volatile("" ::: "memory");
}

// ---------------- fused cast fp32 -> bf16 for x / qkv_w / proj_w ----------------
__global__ __launch_bounds__(256) void cast_all(const float* __restrict__ x,
                                                const float* __restrict__ qw,
                                                const float* __restrict__ pw,
                                                u16* __restrict__ xb, u16* __restrict__ qwb,
                                                u16* __restrict__ pwb) {
  const int bi = blockIdx.x;
  const float* src;
  u16* dst;
  int off;
  if (bi < 4096) {
    src = x; dst = xb; off = bi;
  } else if (bi < 7168) {
    src = qw; dst = qwb; off = bi - 4096;
  } else {
    src = pw; dst = pwb; off = bi - 7168;
  }
  const int i = off * 256 + threadIdx.x;
  const float4 v = ((const float4*)src)[i];
  u16x4 o = {f2bf(v.x), f2bf(v.y), f2bf(v.z), f2bf(v.w)};
  ((u16x4*)dst)[i] = o;
}

// ---------------- 256x256 8-phase GEMM (HK schedule, plain HIP): out = A @ W^T, bf16 out ----
// BM=BN=256, BK(step)=64 split into two 32-wide K-halves; 512 thr = 8 waves (2M x 4N);
// LDS 128 KiB = [2 dbuf][A,B][2 kk][256][32] u16, col^16 (u16) when row&8 swizzle
// applied via pre-swizzled GLOBAL source + swizzled ds_read (both-sides involution, m104).
// 8 phases per 2 K-steps; each phase: {4/8 ds_read_b128 | stage 1 half-tile (2 gload_lds)
// | vmcnt(4) at ph4/ph8 | barrier | setprio(1) 16 MFMA setprio(0) | barrier}.
// Stage ledger (WAR/RAW-safe, verified on paper): ph1:K(t+1).Akk1 ph2:K(t+1).Bkk1
// ph3:K(t+2).Akk0 ph4:K(t+2).Bkk0 ph5:K(t+2).Akk1 ph6:K(t+2).Bkk1 ph7:K(t+3).Akk0
// ph8:K(t+3).Bkk0. vmcnt(4) at ph4 retires prev ph7/ph8 + this ph1/ph2 stages (covers
// ph5/ph7 reads); at ph8 retires ph3..ph6 (covers next ph1/ph3 reads). Last iter:
// stages skip (s>=kSteps) so ph4/ph8 use vmcnt(0).
__global__ __launch_bounds__(512, 2) void gemm256(const u16* __restrict__ A,
                                                  const u16* __restrict__ W,
                                                  u16* __restrict__ outp,
                                                  int M, int N, int K) {
  __shared__ u16 sAB[65536];  // 128 KiB
  const int tid = threadIdx.x;
  const int w = tid >> 6, L = tid & 63;
  const int lo = L & 15, quad = L >> 4;
  const int wm128 = (w >> 2) * 128, wn64 = (w & 3) * 64;
  const int nbn = N >> 8;
  const int nwg = gridDim.x;
  const int cpx = nwg >> 3;  // nwg % 8 == 0
  const int raw = blockIdx.x;
  const int bi = (raw & 7) * cpx + (raw >> 3);  // T1 XCD swizzle (bijective)
  const int bm = bi / nbn, bn = bi - bm * nbn;
  const int m0 = bm << 8, n0 = bn << 8;
  const int kSteps = K >> 6;

  f32x4 acc[8][4];
#pragma unroll
  for (int i = 0; i < 8; ++i)
#pragma unroll
    for (int j = 0; j < 4; ++j) acc[i][j] = 0.f;

  // staging: thread t covers rows r=t>>2 and r+128 of a [256][32] K-half;
  // global col pre-swizzled (^16 u16 when row&8  <=>  tid&32).
  const int rS = tid >> 2;
  const int scol = ((tid & 3) << 3) ^ ((tid & 32) ? 16 : 0);
  const u16* Ap = A + (size_t)(m0 + rS) * K + scol;
  const u16* Wp = W + (size_t)(n0 + rS) * K + scol;
  auto STAGE = [&](int s, int mat, int kk) {
    if (s >= kSteps) return;
    const u16* g = (mat ? Wp : Ap) + s * 64 + kk * 32;
    u16* l = sAB + ((s & 1) << 15) + (mat << 14) + (kk << 13) + tid * 8;
    async16(g, l);
    async16(g + (size_t)128 * K, l + 4096);
  };

  // fragment reads (swizzled): u16 idx = R*32 + (quad*8 ^ (R&8 ? 16 : 0))
  const int qoff = (quad << 3) ^ ((lo & 8) ? 16 : 0);
  auto ldA = [&](int buf, int kk, int mh, int m2) {
    const int R = wm128 + mh * 64 + m2 * 16 + lo;
    return ld8(&sAB[(buf << 15) + (kk << 13) + R * 32 + qoff]);
  };
  auto ldB = [&](int buf, int kk, int nf) {
    const int R = wn64 + nf * 16 + lo;
    return ld8(&sAB[(buf << 15) + 16384 + (kk << 13) + R * 32 + qoff]);
  };

  bf16x8 bF[4];
  auto PH = [&](int buf, int kk, int mh, bool loadB, int sS, int sM, int sK,
                bool dovm, bool last) {
    bf16x8 aF[4];
#pragma unroll
    for (int m2 = 0; m2 < 4; ++m2) aF[m2] = ldA(buf, kk, mh, m2);
    if (loadB) {
#pragma unroll
      for (int nf = 0; nf < 4; ++nf) bF[nf] = ldB(buf, kk, nf);
    }
    STAGE(sS, sM, sK);
    if (dovm) {
      if (last)
        asm volatile("s_waitcnt vmcnt(0)" ::: "memory");
      else
        asm volatile("s_waitcnt vmcnt(4)" ::: "memory");
    }
    barC();
    __builtin_amdgcn_s_setprio(1);
#pragma unroll
    for (int m2 = 0; m2 < 4; ++m2)
#pragma unroll
      for (int nf = 0; nf < 4; ++nf)
        acc[mh * 4 + m2][nf] = mfma16(aF[m2], bF[nf], acc[mh * 4 + m2][nf]);
    __builtin_amdgcn_s_setprio(0);
    barC();
  };

  // prologue: K0 fully + K1 kk0 halves; vmcnt(4) -> K0's 4 halves landed
  STAGE(0, 0, 0); STAGE(0, 1, 0); STAGE(0, 0, 1); STAGE(0, 1, 1);
  STAGE(1, 0, 0); STAGE(1, 1, 0);
  asm volatile("s_waitcnt vmcnt(4)" ::: "memory");
  barC();

  for (int t = 0; t < kSteps; t += 2) {
    const bool last = (t + 2) >= kSteps;
    PH(0, 0, 0, true,  t + 1, 0, 1, false, last);  // ph1
    PH(0, 0, 1, false, t + 1, 1, 1, false, last);  // ph2
    PH(0, 1, 0, true,  t + 2, 0, 0, false, last);  // ph3
    PH(0, 1, 1, false, t + 2, 1, 0, true,  last);  // ph4
    PH(1, 0, 0, true,  t + 2, 0, 1, false, last);  // ph5
    PH(1, 0, 1, false, t + 2, 1, 1, false, last);  // ph6
    PH(1, 1, 0, true,  t + 3, 0, 0, false, last);  // ph7
    PH(1, 1, 1, false, t + 3, 1, 0, true,  last);  // ph8
  }

#pragma unroll
  for (int mf = 0; mf < 8; ++mf) {
    const int m = m0 + wm128 + (mf >> 2) * 64 + (mf & 3) * 16 + quad * 4;
#pragma unroll
    for (int nf = 0; nf < 4; ++nf) {
      const int nn = n0 + wn64 + nf * 16 + lo;
#pragma unroll
      for (int r = 0; r < 4; ++r) outp[(size_t)(m + r) * N + nn] = f2bf(acc[mf][nf][r]);
    }
  }
}

// ---------------- GEMM: out[M,N] = A[M,K] @ W[N,K]^T (bf16 in, fp32 acc) ----------------
// 128x128 tile, BK=32, 256 threads = 4 waves (2x2), double-buffered LDS staging.
// (kept for proj: 256 blocks fills the CU grid better than 256^2 would)
template <int OUT_BF16>
__global__ __launch_bounds__(256) void gemm_bt(const u16* __restrict__ A,
                                               const u16* __restrict__ W,
                                               void* __restrict__ outp,
                                               int M, int N, int K) {
  __shared__ u16 sA[2 * 4096];
  __shared__ u16 sB[2 * 4096];
  const int tid = threadIdx.x;
  const int w = tid >> 6, L = tid & 63;
  const int lo = L & 15, quad = L >> 4;
  const int nb = N >> 7;
  const int bm = blockIdx.x / nb, bn = blockIdx.x - bm * nb;
  const int m0 = bm << 7, n0 = bn << 7;
  const int wm = (w >> 1) << 6, wn = (w & 1) << 6;

  f32x4 acc[4][4];
#pragma unroll
  for (int i = 0; i < 4; ++i)
#pragma unroll
    for (int j = 0; j < 4; ++j) acc[i][j] = 0.f;

  const int r0 = tid >> 2, s0 = tid & 3;
  const int c0 = s0 ^ ((r0 >> 1) & 3);
  const int r1 = r0 + 64;
  const int c1 = s0 ^ ((r1 >> 1) & 3);
  const u16* aP0 = A + (size_t)(m0 + r0) * K + c0 * 8;
  const u16* aP1 = A + (size_t)(m0 + r1) * K + c1 * 8;
  const u16* bP0 = W + (size_t)(n0 + r0) * K + c0 * 8;
  const u16* bP1 = W + (size_t)(n0 + r1) * K + c1 * 8;
  u16* ldA0 = &sA[tid * 8];
  u16* ldA1 = &sA[(tid + 256) * 8];
  u16* ldB0 = &sB[tid * 8];
  u16* ldB1 = &sB[(tid + 256) * 8];

  int raf[4], rbf[4];
#pragma unroll
  for (int mt = 0; mt < 4; ++mt) {
    int r = wm + mt * 16 + lo;
    raf[mt] = r * 32 + ((quad ^ ((r >> 1) & 3)) << 3);
    r = wn + mt * 16 + lo;
    rbf[mt] = r * 32 + ((quad ^ ((r >> 1) & 3)) << 3);
  }

  auto stage = [&](int buf) {
    const int bo = buf << 12;
    async16(aP0, ldA0 + bo);
    async16(aP1, ldA1 + bo);
    async16(bP0, ldB0 + bo);
    async16(bP1, ldB1 + bo);
    aP0 += 32; aP1 += 32; bP0 += 32; bP1 += 32;
  };

  const int kIters = K >> 5;
  stage(0);
  for (int kt = 0; kt < kIters; ++kt) {
    __syncthreads();
    if (kt + 1 < kIters) stage((kt + 1) & 1);
    const int bo = (kt & 1) << 12;
    bf16x8 af[4], bfr[4];
#pragma unroll
    for (int mt = 0; mt < 4; ++mt) af[mt] = ld8(&sA[bo + raf[mt]]);
#pragma unroll
    for (int nt = 0; nt < 4; ++nt) bfr[nt] = ld8(&sB[bo + rbf[nt]]);
#pragma unroll
    for (int mt = 0; mt < 4; ++mt)
#pragma unroll
      for (int nt = 0; nt < 4; ++nt)
        acc[mt][nt] = mfma16(af[mt], bfr[nt], acc[mt][nt]);
  }

#pragma unroll
  for (int mt = 0; mt < 4; ++mt) {
    const int m = m0 + wm + mt * 16 + quad * 4;
#pragma unroll
    for (int nt = 0; nt < 4; ++nt) {
      const int n = n0 + wn + nt * 16 + lo;
#pragma unroll
      for (int r = 0; r < 4; ++r) {
        const size_t off = (size_t)(m + r) * N + n;
        if (OUT_BF16)
          ((u16*)outp)[off] = f2bf(acc[mt][nt][r]);
        else
          ((float*)outp)[off] = acc[mt][nt][r];
      }
    }
  }
}

// ---------------- fused RoPE(Q,K) + V transpose ----------------
// blocks [0,2048): rope, VECTORIZED: 8 bf16 (4 rope pairs) per thread, u16x8 loads/stores;
// blocks [2048,3072): vt LDS transpose.
#define QSCALE 0.18033688011112f  // 0.125 * log2(e)
__global__ __launch_bounds__(256) void ropevt_k(const u16* __restrict__ qkv,
                                                const float* __restrict__ cosb,
                                                const float* __restrict__ sinb,
                                                u16* __restrict__ qo, u16* __restrict__ ko,
                                                u16* __restrict__ vto) {
  __shared__ u16 sT[64 * 64];
  const int tid = threadIdx.x;
  if (blockIdx.x < 2048) {
    const int idx = blockIdx.x * 256 + tid;  // ((b*2048+t)*16+h)*8 + c
    const int c = idx & 7;
    const int h = (idx >> 3) & 15;
    const int t = (idx >> 7) & 2047;
    const int b = idx >> 18;
    const size_t src = (size_t)(b * 2048 + t) * 3072 + h * 64 + c * 8;
    const u16x8 qv = *(const u16x8*)&qkv[src];
    const u16x8 kv = *(const u16x8*)&qkv[src + 1024];
    const f32x4 cv = *(const f32x4*)&cosb[t * 32 + c * 4];
    const f32x4 sv = *(const f32x4*)&sinb[t * 32 + c * 4];
    u16x8 q8, k8;
#pragma unroll
    for (int j = 0; j < 4; ++j) {
      const float cc = cv[j], ss = sv[j];
      const float q0 = bf2f(qv[2 * j]), q1 = bf2f(qv[2 * j + 1]);
      q8[2 * j] = f2bf((q0 * cc - q1 * ss) * QSCALE);
      q8[2 * j + 1] = f2bf((q0 * ss + q1 * cc) * QSCALE);
      const float k0 = bf2f(kv[2 * j]), k1 = bf2f(kv[2 * j + 1]);
      k8[2 * j] = f2bf(k0 * cc - k1 * ss);
      k8[2 * j + 1] = f2bf(k0 * ss + k1 * cc);
    }
    const size_t dst = (size_t)((b * 16 + h) * 2048 + t) * 64 + c * 8;
    *(u16x8*)&qo[dst] = q8;
    *(u16x8*)&ko[dst] = k8;
  } else {
    const int bi = blockIdx.x - 2048;
    const int bh = bi & 31;
    const int t0 = (bi >> 5) << 6;
    const int b = bh >> 4, h = bh & 15;
#pragma unroll
    for (int it = 0; it < 2; ++it) {
      const int id = tid + it * 256;
      const int tr = id >> 3, s = id & 7, c = s ^ (tr & 7);
      async16(qkv + (size_t)(b * 2048 + t0 + tr) * 3072 + 2048 + h * 64 + c * 8, &sT[id * 8]);
    }
    __syncthreads();
#pragma unroll
    for (int it = 0; it < 2; ++it) {
      const int id = tid + it * 256;
      const int d = id >> 3, ct = id & 7;
      u16x8 o;
#pragma unroll
      for (int j = 0; j < 8; ++j) {
        const int t = ct * 8 + j;
        o[j] = sT[t * 64 + (((d >> 3) ^ (t & 7)) << 3) + (d & 7)];
      }
      *(u16x8*)(vto + ((size_t)bh * 64 + d) * 2048 + t0 + ct * 8) = o;
    }
  }
}

// ---------------- causal flash attention, split-KV partials, MAX-FREE softmax ----------------
// 32x32x16 MFMA, 4 waves x 32 q-rows = 128-q blocks, 64-kv tiles; swapped QK^T puts the
// P slice in-lane; P reshapes to PV B-frags in-register via cvt_pk+permlane32_swap (T12);
// l row-sum on the MFMA pipe; T5 setprio around MFMA clusters.
__global__ __launch_bounds__(256, 2) void fattn_part(const u16* __restrict__ qs,
                                                     const u16* __restrict__ ks,
                                                     const u16* __restrict__ vtb,
                                                     u16* __restrict__ opart,
                                                     float* __restrict__ lbuf) {
  __shared__ u16 sK[2 * 4096];   // kv-major rows of 128B, chunk slot = c ^ (kv&7)
  __shared__ u16 sVt[2 * 4096];  // d-major rows of 128B, chunk slot = c ^ (d&7)
  const int tid = threadIdx.x;
  const int w = tid >> 6, L = tid & 63;
  const int col = L & 31, hi = L >> 5;
  const int raw = blockIdx.x;
  const int part = raw & 1;
  const int bh = (raw >> 1) & 31;
  const int qb = 15 - (raw >> 6);  // long blocks launch first
  const int n = 2 * qb + 2;        // kv tiles this block needs (causal)
  const int h0 = qb + 1;
  const int tk0 = part ? h0 : 0;
  const int tk1 = part ? n : h0;
  const size_t hoff = (size_t)bh * (2048 * 64);
  const int q0 = qb << 7;
  const int wq = q0 + w * 32;  // this wave's first q row

  const int kvA = tid >> 3, cA = (tid & 7) ^ (kvA & 7);
  const int idB = tid + 256;
  const int kvB = idB >> 3, cB = (idB & 7) ^ (kvB & 7);
  const u16* kP0 = ks + hoff + (size_t)(tk0 * 64 + kvA) * 64 + cA * 8;
  const u16* kP1 = ks + hoff + (size_t)(tk0 * 64 + kvB) * 64 + cB * 8;
  const u16* vP0 = vtb + hoff + (size_t)kvA * 2048 + tk0 * 64 + cA * 8;
  const u16* vP1 = vtb + hoff + (size_t)kvB * 2048 + tk0 * 64 + cB * 8;
  u16* ldK0 = &sK[tid * 8];
  u16* ldK1 = &sK[idB * 8];
  u16* ldV0 = &sVt[tid * 8];
  u16* ldV1 = &sVt[idB * 8];

  auto stage = [&](int buf) {
    const int bo = buf << 12;
    async16(kP0, ldK0 + bo);
    async16(kP1, ldK1 + bo);
    async16(vP0, ldV0 + bo);
    async16(vP1, ldV1 + bo);
    kP0 += 4096; kP1 += 4096; vP0 += 64; vP1 += 64;
  };

  int kaOff[2][4];
#pragma unroll
  for (int mt = 0; mt < 2; ++mt) {
    const int row = mt * 32 + col;
#pragma unroll
    for (int ksI = 0; ksI < 4; ++ksI)
      kaOff[mt][ksI] = row * 64 + (((ksI * 2 + hi) ^ (row & 7)) << 3);
  }

  bf16x8 qf[4];
#pragma unroll
  for (int ksI = 0; ksI < 4; ++ksI)
    qf[ksI] = ld8(qs + hoff + (size_t)(wq + col) * 64 + ksI * 16 + hi * 8);

  bf16x8 ones;
#pragma unroll
  for (int j = 0; j < 8; ++j) ones[j] = (__bf16)1.0f;

  f32x16 lacc = 0.f;
  f32x16 ot0 = 0.f, ot1 = 0.f;

  const int ntk = tk1 - tk0;
  stage(0);
  for (int it2 = 0; it2 < ntk; ++it2) {
    __syncthreads();
    if (it2 + 1 < ntk) stage((it2 + 1) & 1);
    const int bo = (it2 & 1) << 12;
    const int kt = tk0 + it2;

    if (64 * kt <= wq + 31) {
      f32x16 st0 = 0.f, st1 = 0.f;
      __builtin_amdgcn_s_setprio(1);
#pragma unroll
      for (int ksI = 0; ksI < 4; ++ksI) {
        st0 = mfma32(ld8(&sK[bo + kaOff[0][ksI]]), qf[ksI], st0);
        st1 = mfma32(ld8(&sK[bo + kaOff[1][ksI]]), qf[ksI], st1);
      }
      __builtin_amdgcn_s_setprio(0);
      if (64 * kt + 63 > wq) {  // diagonal tile: causal mask
        const int qg = wq + col;
        const int kvb = 64 * kt + 4 * hi;
#pragma unroll
        for (int r = 0; r < 16; ++r) {
          const int kvr = kvb + (r & 3) + 8 * (r >> 2);
          if (kvr > qg) st0[r] = -3.0e38f;
          if (kvr + 32 > qg) st1[r] = -3.0e38f;
        }
      }
      bf16x8 pf[4];
#pragma unroll
      for (int mt = 0; mt < 2; ++mt) {
        const f32x16 sv = mt ? st1 : st0;
        f32x16 p;
#pragma unroll
        for (int r = 0; r < 16; ++r) p[r] = __builtin_amdgcn_exp2f(sv[r]);
        {
          unsigned x0 = pkbf(p[0], p[1]), x1 = pkbf(p[2], p[3]);
          unsigned y0 = pkbf(p[4], p[5]), y1 = pkbf(p[6], p[7]);
          u32x2 r02 = __builtin_amdgcn_permlane32_swap(x0, y0, false, false);
          u32x2 r13 = __builtin_amdgcn_permlane32_swap(x1, y1, false, false);
          u32x4 wv = {r02[0], r13[0], r02[1], r13[1]};
          pf[2 * mt] = __builtin_bit_cast(bf16x8, wv);
        }
        {
          unsigned x0 = pkbf(p[8], p[9]), x1 = pkbf(p[10], p[11]);
          unsigned y0 = pkbf(p[12], p[13]), y1 = pkbf(p[14], p[15]);
          u32x2 r02 = __builtin_amdgcn_permlane32_swap(x0, y0, false, false);
          u32x2 r13 = __builtin_amdgcn_permlane32_swap(x1, y1, false, false);
          u32x4 wv = {r02[0], r13[0], r02[1], r13[1]};
          pf[2 * mt + 1] = __builtin_bit_cast(bf16x8, wv);
        }
      }
      __builtin_amdgcn_s_setprio(1);
#pragma unroll
      for (int ksI = 0; ksI < 4; ++ksI) lacc = mfma32(ones, pf[ksI], lacc);
#pragma unroll
      for (int ksI = 0; ksI < 4; ++ksI) {
        ot0 = mfma32(ld8(&sVt[bo + kaOff[0][ksI]]), pf[ksI], ot0);
        ot1 = mfma32(ld8(&sVt[bo + kaOff[1][ksI]]), pf[ksI], ot1);
      }
      __builtin_amdgcn_s_setprio(0);
    }
  }

  const int q = wq + col;
  const int pq = bh * 32 + (q >> 6);
  u16* ob = opart + (size_t)(part * 1024 + pq) * 4096 + (size_t)(q & 63) * 64;
#pragma unroll
  for (int mtd = 0; mtd < 2; ++mtd) {
    const f32x16 o = mtd ? ot1 : ot0;
#pragma unroll
    for (int rg = 0; rg < 4; ++rg) {
      const int d0 = mtd * 32 + rg * 8 + hi * 4;
      u16x4 ok = {f2bf(o[rg * 4 + 0]), f2bf(o[rg * 4 + 1]),
                  f2bf(o[rg * 4 + 2]), f2bf(o[rg * 4 + 3])};
      *(u16x4*)&ob[d0] = ok;
    }
  }
  if (hi == 0) lbuf[(size_t)(part * 1024 + pq) * 64 + (q & 63)] = lacc[0];
}

// ---------------- merge the two kv-half partials -> attn (B,T,C) bf16 ----------------
__global__ __launch_bounds__(256) void fattn_merge(const u16* __restrict__ opart,
                                                   const float* __restrict__ lbuf,
                                                   u16* __restrict__ aout) {
  const int pq = blockIdx.x;
  const int bh = pq >> 5, qi = pq & 31;
  const int b = bh >> 4, h = bh & 15;
  const int tid = threadIdx.x;
#pragma unroll
  for (int it = 0; it < 2; ++it) {
    const int idx = tid + it * 256;
    const int q = idx >> 3, d0 = (idx & 7) * 8;
    const float l0 = lbuf[(size_t)pq * 64 + q];
    const float l1 = lbuf[(size_t)(1024 + pq) * 64 + q];
    const float inv = 1.f / (l0 + l1);
    const u16x8 o0 = *(const u16x8*)&opart[(size_t)pq * 4096 + q * 64 + d0];
    const u16x8 o1 = *(const u16x8*)&opart[(size_t)(1024 + pq) * 4096 + q * 64 + d0];
    u16x8 o;
#pragma unroll
    for (int j = 0; j < 8; ++j) o[j] = f2bf((bf2f(o0[j]) + bf2f(o1[j])) * inv);
    *(u16x8*)&aout[((size_t)(b * 2048 + qi * 64 + q)) * 1024 + h * 64 + d0] = o;
  }
}

extern "C" void kernel_launch(void* const* d_in, const int* in_sizes, int n_in,
                              void* d_out, int out_size, void* d_ws, size_t ws_size,
                              hipStream_t stream) {
  const float* x = (const float*)d_in[0];
  const float* fcos = (const float*)d_in[1];
  const float* fsin = (const float*)d_in[2];
  const float* qkvw = (const float*)d_in[3];
  const float* projw = (const float*)d_in[4];
  float* out = (float*)d_out;

  char* ws = (char*)d_ws;
  u16* x_bf = (u16*)(ws);                    // 8 MB  (4096x1024)
  u16* qkvw_bf = (u16*)(ws + (8u << 20));    // 6 MB  (3072x1024)
  u16* projw_bf = (u16*)(ws + (14u << 20));  // 2 MB  (1024x1024)
  u16* qkv_bf = (u16*)(ws + (16u << 20));    // 24 MB (4096x3072), dead after ropevt
  u16* q_bf = (u16*)(ws + (40u << 20));      // 8 MB  (B,H,T,D)
  u16* k_bf = (u16*)(ws + (48u << 20));      // 8 MB  (B,H,T,D)
  u16* vt = (u16*)(ws + (56u << 20));        // 8 MB  (B,H,D,T)
  u16* attn_bf = (u16*)(ws + (64u << 20));   // 8 MB  (B,T,C)
  // overlays on the dead qkv_bf region:
  u16* opart = (u16*)(ws + (16u << 20));     // 16 MB [2][1024][64q][64d] bf16
  float* lbuf = (float*)(ws + (32u << 20));  // 0.5 MB [2][1024][64q]

  cast_all<<<8192, 256, 0, stream>>>(x, qkvw, projw, x_bf, qkvw_bf, projw_bf);
  gemm256<<<192, 512, 0, stream>>>(x_bf, qkvw_bf, qkv_bf, 4096, 3072, 1024);
  ropevt_k<<<3072, 256, 0, stream>>>(qkv_bf, fcos, fsin, q_bf, k_bf, vt);
  fattn_part<<<1024, 256, 0, stream>>>(q_bf, k_bf, vt, opart, lbuf);
  fattn_merge<<<1024, 256, 0, stream>>>(opart, lbuf, attn_bf);
  gemm_bt<0><<<256, 256, 0, stream>>>(attn_bf, projw_bf, (void*)out, 4096, 1024, 1024);
}